// Round 2
// baseline (98.521 us; speedup 1.0000x reference)
//
#include <hip/hip_runtime.h>
#include <stdint.h>

#define BB 128
#define SS 4096
#define DD 64
#define HH 256

typedef short bf16x8 __attribute__((ext_vector_type(8)));
typedef float f32x16 __attribute__((ext_vector_type(16)));

__device__ __forceinline__ uint32_t cvt_pk_bf16(float lo, float hi) {
  uint32_t r;
  asm("v_cvt_pk_bf16_f32 %0, %1, %2" : "=v"(r) : "v"(lo), "v"(hi));
  return r;
}

__device__ __forceinline__ float bflo(uint32_t w) {
  union { uint32_t u; float f; } c; c.u = w << 16; return c.f;
}
__device__ __forceinline__ float bfhi(uint32_t w) {
  union { uint32_t u; float f; } c; c.u = w & 0xffff0000u; return c.f;
}

__device__ __forceinline__ float silu_f(float v) {
  float e = __expf(-v);
  return v * __builtin_amdgcn_rcpf(1.0f + e);
}

__device__ __forceinline__ void gload16(const void* g, void* l) {
  __builtin_amdgcn_global_load_lds(
      (const __attribute__((address_space(1))) void*)g,
      (__attribute__((address_space(3))) void*)l, 16, 0, 0);
}

// ---------------- pre-pass: transpose + f32->bf16 weights into workspace ----
// W1 f32 [B][64][256] -> W1t bf16 [B][256][64]  (GEMM1 A, K=d contiguous)
// W2 f32 [B][256][64] -> W2t bf16 [B][64][256]  (GEMM2 A, K=h contiguous)
__global__ __launch_bounds__(256) void transpose_w(
    const float* __restrict__ W1, const float* __restrict__ W2,
    ushort* __restrict__ W1t, ushort* __restrict__ W2t) {
  int g = blockIdx.x * 256 + threadIdx.x;
  const int half = (BB * DD * HH) / 8;  // 262144
  float v[8];
  if (g < half) {
    size_t e = (size_t)g * 8;              // W1t element, [b][h][d]
    int b = (int)(e >> 14);
    int rem = (int)(e & 16383);
    int h = rem >> 6;
    int d0 = rem & 63;
    const float* src = W1 + ((size_t)b << 14) + h;  // + d*256
#pragma unroll
    for (int j = 0; j < 8; ++j) v[j] = src[(size_t)(d0 + j) << 8];
    uint4 o;
    o.x = cvt_pk_bf16(v[0], v[1]); o.y = cvt_pk_bf16(v[2], v[3]);
    o.z = cvt_pk_bf16(v[4], v[5]); o.w = cvt_pk_bf16(v[6], v[7]);
    *reinterpret_cast<uint4*>(W1t + e) = o;
  } else if (g < 2 * half) {
    size_t e = (size_t)(g - half) * 8;     // W2t element, [b][d][h]
    int b = (int)(e >> 14);
    int rem = (int)(e & 16383);
    int d = rem >> 8;
    int h0 = rem & 255;
    const float* src = W2 + ((size_t)b << 14) + d;  // + h*64
#pragma unroll
    for (int j = 0; j < 8; ++j) v[j] = src[(size_t)(h0 + j) << 6];
    uint4 o;
    o.x = cvt_pk_bf16(v[0], v[1]); o.y = cvt_pk_bf16(v[2], v[3]);
    o.z = cvt_pk_bf16(v[4], v[5]); o.w = cvt_pk_bf16(v[6], v[7]);
    *reinterpret_cast<uint4*>(W2t + e) = o;
  }
}

// ---------------- main fused kernel ----------------
// Per WG: b fixed, 512 s-rows, 8 waves x 64 rows.
// LDS: [0,32K)    W1t[h][d] bf16, 128B rows, byte ^= ((byte>>7)&7)<<4
//      [32K,64K)  W2t[d][h] bf16, 512B rows, byte ^= ((byte>>9)&7)<<4
//      [64K,128K) per-wave 8KB scratch: x bf16 tile -> h bf16 tile -> out f32
__global__ __launch_bounds__(512, 2) void mlp_fused(
    const float* __restrict__ xg, const ushort* __restrict__ w1t,
    const ushort* __restrict__ w2t, float* __restrict__ outg) {
  __shared__ int4 lds4[131072 / 16];
  char* lds = (char*)lds4;

  const int tid = threadIdx.x;
  const int wave = tid >> 6;
  const int lane = tid & 63;
  const int l31 = lane & 31;
  const int g5 = lane >> 5;

  // XCD-aware swizzle: 1024 blocks, 8 XCDs -> XCD k owns b in [16k,16k+16)
  int raw = blockIdx.x;
  int logical = (raw & 7) * 128 + (raw >> 3);
  const int b = logical >> 3;
  const int st = logical & 7;
  const int s_base = st * 512 + wave * 64;

  // stage W1t / W2t (pre-swizzled global source, linear LDS dest)
  const char* w1b = (const char*)(w1t + ((size_t)b << 14));
  const char* w2b = (const char*)(w2t + ((size_t)b << 14));
#pragma unroll
  for (int r = 0; r < 4; ++r) {
    uint32_t o = (uint32_t)(r * 8192 + wave * 1024 + lane * 16);
    gload16(w1b + (o ^ (((o >> 7) & 7) << 4)), lds + (r * 8192 + wave * 1024));
    gload16(w2b + (o ^ (((o >> 9) & 7) << 4)),
            lds + 32768 + (r * 8192 + wave * 1024));
  }

  char* hbase = lds + 65536 + wave * 8192;

  // stage x tile: f32 global (coalesced) -> bf16 LDS [64 s][64 d], swizzled
  const float* xb = xg + (((size_t)b * SS + s_base) << 6);
#pragma unroll
  for (int it = 0; it < 8; ++it) {
    int e = it * 512 + lane * 8;
    int s = e >> 6, d0 = e & 63;
    float4 fa = *reinterpret_cast<const float4*>(xb + ((size_t)s << 6) + d0);
    float4 fb = *reinterpret_cast<const float4*>(xb + ((size_t)s << 6) + d0 + 4);
    uint4 pk;
    pk.x = cvt_pk_bf16(fa.x, fa.y); pk.y = cvt_pk_bf16(fa.z, fa.w);
    pk.z = cvt_pk_bf16(fb.x, fb.y); pk.w = cvt_pk_bf16(fb.z, fb.w);
    uint32_t byte = (uint32_t)(s * 128 + d0 * 2);
    byte ^= (uint32_t)(s & 7) << 4;
    *reinterpret_cast<uint4*>(hbase + byte) = pk;
  }

  // x B-frags for GEMM1: lane holds x[s=32nt+l31][d = 16kc+8g5 .. +7]
  bf16x8 bx[2][4];
#pragma unroll
  for (int nt = 0; nt < 2; ++nt)
#pragma unroll
    for (int kc = 0; kc < 4; ++kc) {
      int s = nt * 32 + l31;
      uint32_t byte = (uint32_t)(s * 128 + kc * 32 + g5 * 16);
      byte ^= (uint32_t)(s & 7) << 4;
      bx[nt][kc] = *reinterpret_cast<const bf16x8*>(hbase + byte);
    }

  // acc init = residual x^T (bf16-rounded):
  // acc[mt][nt][4q+j] = x[s=32nt+l31][d = 32mt + 8q + 4g5 + j]
  f32x16 acc[2][2];
#pragma unroll
  for (int mt = 0; mt < 2; ++mt)
#pragma unroll
    for (int nt = 0; nt < 2; ++nt) {
      int s = nt * 32 + l31;
      uint32_t sw = (uint32_t)(s & 7) << 4;
#pragma unroll
      for (int q = 0; q < 4; ++q) {
        uint32_t byte = (uint32_t)(s * 128 + mt * 64 + q * 16 + g5 * 8);
        byte ^= sw;
        uint2 w = *reinterpret_cast<const uint2*>(hbase + byte);
        acc[mt][nt][4 * q + 0] = bflo(w.x);
        acc[mt][nt][4 * q + 1] = bfhi(w.x);
        acc[mt][nt][4 * q + 2] = bflo(w.y);
        acc[mt][nt][4 * q + 3] = bfhi(w.y);
      }
    }
  __builtin_amdgcn_sched_barrier(0);  // keep x reads before h-stash writes
  __syncthreads();                    // W staging (gload_lds) complete

  const f32x16 vzero = {0.f, 0.f, 0.f, 0.f, 0.f, 0.f, 0.f, 0.f,
                        0.f, 0.f, 0.f, 0.f, 0.f, 0.f, 0.f, 0.f};

#pragma unroll
  for (int hb = 0; hb < 4; ++hb) {
    // ---- GEMM1 (swapped): h^T = W1t_block * x^T ----
    bf16x8 a1[2][4];
#pragma unroll
    for (int mt = 0; mt < 2; ++mt)
#pragma unroll
      for (int kc = 0; kc < 4; ++kc) {
        int hrow = hb * 64 + mt * 32 + l31;
        uint32_t byte = (uint32_t)hrow * 128 + (uint32_t)(kc * 32 + g5 * 16);
        byte ^= (uint32_t)(hrow & 7) << 4;
        a1[mt][kc] = *reinterpret_cast<const bf16x8*>(lds + byte);
      }
    f32x16 ah[2][2];
    ah[0][0] = vzero; ah[0][1] = vzero; ah[1][0] = vzero; ah[1][1] = vzero;
#pragma unroll
    for (int kc = 0; kc < 4; ++kc)
#pragma unroll
      for (int mt = 0; mt < 2; ++mt)
#pragma unroll
        for (int nt = 0; nt < 2; ++nt)
          ah[mt][nt] = __builtin_amdgcn_mfma_f32_32x32x16_bf16(
              a1[mt][kc], bx[nt][kc], ah[mt][nt], 0, 0, 0);

    // ---- silu + pack bf16 + stash (wave-private, no barrier) ----
    // C/D 32x32: col(s)=l31, row(h') = (reg&3) + 8*(reg>>2) + 4*g5
#pragma unroll
    for (int mt = 0; mt < 2; ++mt)
#pragma unroll
      for (int nt = 0; nt < 2; ++nt) {
        int s_loc = nt * 32 + l31;
        uint32_t sw = (uint32_t)(s_loc & 7) << 4;
#pragma unroll
        for (int q = 0; q < 4; ++q) {
          float t0 = silu_f(ah[mt][nt][4 * q + 0]);
          float t1 = silu_f(ah[mt][nt][4 * q + 1]);
          float t2 = silu_f(ah[mt][nt][4 * q + 2]);
          float t3 = silu_f(ah[mt][nt][4 * q + 3]);
          uint32_t p0 = cvt_pk_bf16(t0, t1);
          uint32_t p1 = cvt_pk_bf16(t2, t3);
          uint32_t byte =
              (uint32_t)s_loc * 128 + (uint32_t)(mt * 64 + q * 16 + g5 * 8);
          byte ^= sw;
          *reinterpret_cast<uint2*>(hbase + byte) = make_uint2(p0, p1);
        }
      }

    // ---- GEMM2 (swapped): out^T += W2t_block * h^T ----
    bf16x8 a2[2][4], bh[2][4];
#pragma unroll
    for (int mt = 0; mt < 2; ++mt)
#pragma unroll
      for (int kc = 0; kc < 4; ++kc) {
        int drow = mt * 32 + l31;
        uint32_t byte = (uint32_t)drow * 512 +
                        (uint32_t)(hb * 128 + kc * 32 + g5 * 16);
        byte ^= (uint32_t)(drow & 7) << 4;
        a2[mt][kc] = *reinterpret_cast<const bf16x8*>(lds + 32768 + byte);
      }
#pragma unroll
    for (int nt = 0; nt < 2; ++nt)
#pragma unroll
      for (int kc = 0; kc < 4; ++kc) {
        int s_loc = nt * 32 + l31;
        uint32_t byte = (uint32_t)s_loc * 128 + (uint32_t)(kc * 32 + g5 * 16);
        byte ^= (uint32_t)(s_loc & 7) << 4;
        bh[nt][kc] = *reinterpret_cast<const bf16x8*>(hbase + byte);
      }
#pragma unroll
    for (int kc = 0; kc < 4; ++kc)
#pragma unroll
      for (int mt = 0; mt < 2; ++mt)
#pragma unroll
        for (int nt = 0; nt < 2; ++nt)
          acc[mt][nt] = __builtin_amdgcn_mfma_f32_32x32x16_bf16(
              a2[mt][kc], bh[nt][kc], acc[mt][nt], 0, 0, 0);
  }

  // ---- epilogue: bounce f32 out^T tile -> coalesced f32 stores ----
  // two passes (nt), each 32 s-rows x 64 d f32 = 8 KB
#pragma unroll
  for (int nt = 0; nt < 2; ++nt) {
    int s_loc = l31;
    uint32_t sw = (uint32_t)(s_loc & 7) << 4;
#pragma unroll
    for (int mt = 0; mt < 2; ++mt)
#pragma unroll
      for (int q = 0; q < 4; ++q) {
        uint32_t byte =
            (uint32_t)s_loc * 256 + (uint32_t)(mt * 128 + q * 32 + g5 * 16);
        byte ^= sw;
        float4 v;
        v.x = acc[mt][nt][4 * q + 0];
        v.y = acc[mt][nt][4 * q + 1];
        v.z = acc[mt][nt][4 * q + 2];
        v.w = acc[mt][nt][4 * q + 3];
        *reinterpret_cast<float4*>(hbase + byte) = v;
      }
    __builtin_amdgcn_sched_barrier(0);
#pragma unroll
    for (int it = 0; it < 8; ++it) {
      uint32_t o = (uint32_t)(it * 1024 + lane * 16);
      uint32_t row = o >> 8;
      uint32_t byte = o ^ ((row & 7) << 4);
      float4 v = *reinterpret_cast<const float4*>(hbase + byte);
      size_t s = (size_t)s_base + nt * 32 + row;
      size_t goff = (((size_t)b * SS + s) << 6) + ((o & 255) >> 2);
      *reinterpret_cast<float4*>(outg + goff) = v;
    }
    __builtin_amdgcn_sched_barrier(0);
  }
}

extern "C" void kernel_launch(void* const* d_in, const int* in_sizes, int n_in,
                              void* d_out, int out_size, void* d_ws, size_t ws_size,
                              hipStream_t stream) {
  const float* x  = (const float*)d_in[0];
  const float* W1 = (const float*)d_in[1];
  const float* W2 = (const float*)d_in[2];
  float* out = (float*)d_out;

  ushort* W1t = (ushort*)d_ws;                       // bf16 [B][256][64]
  ushort* W2t = W1t + (size_t)BB * DD * HH;          // bf16 [B][64][256]

  transpose_w<<<2048, 256, 0, stream>>>(W1, W2, W1t, W2t);
  mlp_fused<<<1024, 512, 0, stream>>>(x, W1t, W2t, out);
}